// Round 1
// baseline (1034.031 us; speedup 1.0000x reference)
//
#include <hip/hip_runtime.h>
#include <math.h>

#define NPTS 4096
#define CDIM 512
#define BM 32
#define BN 256
#define BK 32
#define NT 256

// ---------------- sq kernel: sq[row] = sum_c f[row][c]^2 ----------------
__global__ __launch_bounds__(256) void sq_kernel(const float* __restrict__ x,
                                                 float* __restrict__ sq) {
    int wid  = threadIdx.x >> 6;   // wave id 0..3
    int lane = threadIdx.x & 63;
    int row  = blockIdx.x * 4 + wid;          // 0..16383
    const float* f = x + (size_t)row * CDIM;
    float4 v0 = *(const float4*)(f + lane * 8);
    float4 v1 = *(const float4*)(f + lane * 8 + 4);
    float s = v0.x*v0.x + v0.y*v0.y + v0.z*v0.z + v0.w*v0.w
            + v1.x*v1.x + v1.y*v1.y + v1.z*v1.z + v1.w*v1.w;
    #pragma unroll
    for (int o = 32; o > 0; o >>= 1) s += __shfl_xor(s, o);
    if (lane == 0) sq[row] = s;
}

// ---------------- main fused kernel ----------------
// Block: 256 threads = (ty 0..3) x (tx 0..63). Rows: brow + ty*8 + r (r<8).
// Cols: ct*BN + tx*4 + q (q<4). K staged in LDS chunks of 32.
__global__ __launch_bounds__(NT, 2) void fcm_kernel(const float* __restrict__ x,
                                                    const float* __restrict__ sq,
                                                    float* __restrict__ out) {
    __shared__ __align__(16) float a_s[BK][BM + 4];   // k-major, stride 36
    __shared__ __align__(16) float b_s[BK][BN + 4];   // k-major, stride 260

    const int tid = threadIdx.x;
    const int ty  = tid >> 6;    // 0..3
    const int tx  = tid & 63;    // 0..63

    const int brow  = blockIdx.x * BM;        // flat row base 0..16383
    const int batch = brow >> 12;             // /4096
    const int irow  = brow & (NPTS - 1);
    const float* f   = x  + (size_t)batch * NPTS * CDIM;
    const float* sqb = sq + batch * NPTS;

    float sr[8];
    #pragma unroll
    for (int r = 0; r < 8; ++r) sr[r] = sqb[irow + ty * 8 + r];

    float m0[8], m1[8], m2[8], mx[8];
    #pragma unroll
    for (int r = 0; r < 8; ++r) {
        m0[r] = 3.402823466e+38f; m1[r] = 3.402823466e+38f;
        m2[r] = 3.402823466e+38f; mx[r] = 0.0f;
    }

    for (int ct = 0; ct < NPTS / BN; ++ct) {
        const int cbase = ct * BN;
        float acc[8][4];
        #pragma unroll
        for (int r = 0; r < 8; ++r)
            #pragma unroll
            for (int q = 0; q < 4; ++q) acc[r][q] = 0.0f;

        for (int kc = 0; kc < CDIM; kc += BK) {
            // --- stage A: 32 rows x 32 k, transposed to k-major ---
            {
                int row = tid >> 3, l8 = tid & 7;
                float4 v = *(const float4*)(f + (size_t)(irow + row) * CDIM + kc + l8 * 4);
                a_s[l8 * 4 + 0][row] = v.x;
                a_s[l8 * 4 + 1][row] = v.y;
                a_s[l8 * 4 + 2][row] = v.z;
                a_s[l8 * 4 + 3][row] = v.w;
            }
            // --- stage B: 256 cols x 32 k, transposed to k-major ---
            {
                int colb = tid >> 2, l4 = tid & 3;
                #pragma unroll
                for (int it = 0; it < 4; ++it) {
                    int col = colb + 64 * it;
                    const float* p = f + (size_t)(cbase + col) * CDIM + kc + l4 * 8;
                    float4 v0 = *(const float4*)p;
                    float4 v1 = *(const float4*)(p + 4);
                    b_s[l4 * 8 + 0][col] = v0.x;
                    b_s[l4 * 8 + 1][col] = v0.y;
                    b_s[l4 * 8 + 2][col] = v0.z;
                    b_s[l4 * 8 + 3][col] = v0.w;
                    b_s[l4 * 8 + 4][col] = v1.x;
                    b_s[l4 * 8 + 5][col] = v1.y;
                    b_s[l4 * 8 + 6][col] = v1.z;
                    b_s[l4 * 8 + 7][col] = v1.w;
                }
            }
            __syncthreads();
            #pragma unroll
            for (int k = 0; k < BK; ++k) {
                float a0[8], b0[4];
                *(float4*)&a0[0] = *(const float4*)&a_s[k][ty * 8];
                *(float4*)&a0[4] = *(const float4*)&a_s[k][ty * 8 + 4];
                *(float4*)&b0[0] = *(const float4*)&b_s[k][tx * 4];
                #pragma unroll
                for (int r = 0; r < 8; ++r)
                    #pragma unroll
                    for (int q = 0; q < 4; ++q)
                        acc[r][q] = fmaf(a0[r], b0[q], acc[r][q]);
            }
            __syncthreads();
        }

        // --- epilogue: fold this column tile into top-3 min / max ---
        #pragma unroll
        for (int q = 0; q < 4; ++q) {
            float sc = sqb[cbase + tx * 4 + q];
            #pragma unroll
            for (int r = 0; r < 8; ++r) {
                float d2v = fmaf(-2.0f, acc[r][q], sr[r] + sc);
                d2v = fmaxf(d2v, 0.0f);
                float d = sqrtf(d2v + 1e-12f);
                // insert d into sorted triple (m0<=m1<=m2), branchless
                float lo = fminf(m0[r], d), hi = fmaxf(m0[r], d);
                m0[r] = lo;
                float lo1 = fminf(m1[r], hi), hi1 = fmaxf(m1[r], hi);
                m1[r] = lo1;
                m2[r] = fminf(m2[r], hi1);
                mx[r] = fmaxf(mx[r], d);
            }
        }
    }

    // --- butterfly merge across the 64 lanes of the wave (all share rows) ---
    #pragma unroll
    for (int s = 1; s < 64; s <<= 1) {
        #pragma unroll
        for (int r = 0; r < 8; ++r) {
            float b0v = __shfl_xor(m0[r], s);
            float b1v = __shfl_xor(m1[r], s);
            float b2v = __shfl_xor(m2[r], s);
            float bmv = __shfl_xor(mx[r], s);
            float n0 = fminf(m0[r], b0v);
            float n1 = fminf(fmaxf(m0[r], b0v), fminf(m1[r], b1v));
            float n2 = fminf(fminf(m2[r], b2v),
                             fminf(fmaxf(m0[r], b1v), fmaxf(m1[r], b0v)));
            m0[r] = n0; m1[r] = n1; m2[r] = n2;
            mx[r] = fmaxf(mx[r], bmv);
        }
    }

    if (tx == 0) {
        #pragma unroll
        for (int r = 0; r < 8; ++r) {
            int grow = brow + ty * 8 + r;
            float d1 = m1[r], d2nd = m2[r], dmaxv = mx[r];
            float pred = (d1 / d2nd < 0.6f) ? 2.0f / (1.0f + expf(d1))
                                            : 2.0f / (1.0f + 2.0f * expf(dmaxv));
            out[grow] = pred;
        }
    }
}

extern "C" void kernel_launch(void* const* d_in, const int* in_sizes, int n_in,
                              void* d_out, int out_size, void* d_ws, size_t ws_size,
                              hipStream_t stream) {
    const float* x = (const float*)d_in[0];
    float* out = (float*)d_out;
    float* sqw = (float*)d_ws;   // 16384 floats = 64 KB scratch

    sq_kernel<<<dim3(4096), dim3(256), 0, stream>>>(x, sqw);
    fcm_kernel<<<dim3(512), dim3(NT), 0, stream>>>(x, sqw, out);
}

// Round 2
// 220.883 us; speedup vs baseline: 4.6813x; 4.6813x over previous
//
#include <hip/hip_runtime.h>
#include <math.h>

#define NPTS 4096
#define CDIM 512
#define NROWS 16384

typedef _Float16 half_t;
typedef _Float16 half8 __attribute__((ext_vector_type(8)));
typedef float f32x4 __attribute__((ext_vector_type(4)));

__device__ inline void gl_lds16(const void* g, void* l) {
    __builtin_amdgcn_global_load_lds(
        (const __attribute__((address_space(1))) uint32_t*)g,
        (__attribute__((address_space(3))) uint32_t*)l, 16, 0, 0);
}

// ============================================================================
// Path A (MFMA): prep -> fcm_mfma -> combine
// ============================================================================

// prep: per row, compute sq = sum x^2 (fp32) and write hi/lo f16 planes in the
// swizzled-chunk image layout: byte(row,ch) = row*1024 + (ch>>5)*64 +
// (((ch>>3)&3) ^ (row&3))*16 + (ch&7)*2. This is exactly the LDS layout the
// main kernel wants, so global_load_lds can copy linearly (dest = base+lane*16).
__global__ __launch_bounds__(256) void prep_kernel(const float* __restrict__ x,
                                                   half_t* __restrict__ hi,
                                                   half_t* __restrict__ lo,
                                                   float* __restrict__ sq) {
    const int wv = threadIdx.x >> 6, l = threadIdx.x & 63;
    const int row = blockIdx.x * 4 + wv;
    const float* f = x + (size_t)row * CDIM;
    float4 v0 = *(const float4*)(f + l * 8);
    float4 v1 = *(const float4*)(f + l * 8 + 4);
    float xs[8] = {v0.x, v0.y, v0.z, v0.w, v1.x, v1.y, v1.z, v1.w};
    half8 h, lw;
    float s = 0.0f;
    #pragma unroll
    for (int i = 0; i < 8; ++i) {
        float v = xs[i];
        s = fmaf(v, v, s);
        half_t hh = (half_t)v;
        h[i] = hh;
        lw[i] = (half_t)(v - (float)hh);
    }
    #pragma unroll
    for (int o = 32; o > 0; o >>= 1) s += __shfl_xor(s, o);
    const int sl = (l & 3) ^ (row & 3);              // swizzled 16B slot
    const size_t ob = (size_t)row * CDIM + (l >> 2) * 32 + sl * 8;
    *(half8*)(hi + ob) = h;
    *(half8*)(lo + ob) = lw;
    if (l == 0) sq[row] = s;
}

// main: 128x128 tile per block, 4 waves (2x2, 64x64 each), K-chunks of 32 ch,
// double-buffered LDS staged via global_load_lds from the preconverted images.
// 3 MFMA passes (hh, hl, lh) per fragment pair accumulate the fp32 dot.
// Top-3-min / max folded per column tile in the d^2 domain (sqrt deferred).
__global__ __launch_bounds__(256, 2) void fcm_mfma(const half_t* __restrict__ hi,
                                                   const half_t* __restrict__ lo,
                                                   const float* __restrict__ sq,
                                                   float* __restrict__ part) {
    __shared__ __align__(16) char smem[2][4][8192];  // [buf][ah,al,bh,bl][8KB]
    const int tid = threadIdx.x, wv = tid >> 6, l = tid & 63;
    const int wm = wv >> 1, wn = wv & 1;
    const int bid = blockIdx.x;
    const int rb = bid & 127, strip = bid >> 7;
    const int r0 = rb * 128;
    const int batch = r0 >> 12;
    const int cflat0 = (batch << 12) + strip * 1024;

    const char* hb = (const char*)hi;
    const char* lb = (const char*)lo;

    float sr[16];
    #pragma unroll
    for (int mi = 0; mi < 4; ++mi)
        #pragma unroll
        for (int j = 0; j < 4; ++j)
            sr[mi * 4 + j] = sq[r0 + wm * 64 + mi * 16 + (l >> 4) * 4 + j];

    float st0[16], st1[16], st2[16], stx[16];        // d^2 domain
    #pragma unroll
    for (int i = 0; i < 16; ++i) {
        st0[i] = 3.402823466e+38f; st1[i] = 3.402823466e+38f;
        st2[i] = 3.402823466e+38f; stx[i] = 0.0f;
    }

#define STAGE(buf, kc) do {                                                    \
        _Pragma("unroll")                                                      \
        for (int i_ = 0; i_ < 2; ++i_) {                                       \
            int destb_ = i_ * 4096 + wv * 1024;                                \
            int db_ = destb_ + l * 16;                                         \
            int trow_ = db_ >> 6, off_ = db_ & 63;                             \
            size_t asrc_ = (size_t)(r0 + trow_) * 1024 + (size_t)(kc) * 64 + off_; \
            size_t bsrc_ = (size_t)(cb + trow_) * 1024 + (size_t)(kc) * 64 + off_; \
            gl_lds16(hb + asrc_, &smem[buf][0][destb_]);                       \
            gl_lds16(lb + asrc_, &smem[buf][1][destb_]);                       \
            gl_lds16(hb + bsrc_, &smem[buf][2][destb_]);                       \
            gl_lds16(lb + bsrc_, &smem[buf][3][destb_]);                       \
        } } while (0)

    for (int ct = 0; ct < 8; ++ct) {
        const int cb = cflat0 + ct * 128;
        f32x4 acc[4][4];
        #pragma unroll
        for (int mi = 0; mi < 4; ++mi)
            #pragma unroll
            for (int ni = 0; ni < 4; ++ni)
                #pragma unroll
                for (int j = 0; j < 4; ++j) acc[mi][ni][j] = 0.0f;

        STAGE(0, 0);
        __syncthreads();
        #pragma unroll 2
        for (int kc = 0; kc < 16; ++kc) {
            const int cur = kc & 1;
            if (kc < 15) STAGE(cur ^ 1, kc + 1);
            half8 ah[4], al[4], bhv[4], blv[4];
            #pragma unroll
            for (int q = 0; q < 4; ++q) {
                {
                    int row = (wm * 4 + q) * 16 + (l & 15);
                    int sfw = ((l >> 4) ^ (row & 3)) & 3;
                    ah[q] = *(const half8*)&smem[cur][0][row * 64 + sfw * 16];
                    al[q] = *(const half8*)&smem[cur][1][row * 64 + sfw * 16];
                }
                {
                    int row = (wn * 4 + q) * 16 + (l & 15);
                    int sfw = ((l >> 4) ^ (row & 3)) & 3;
                    bhv[q] = *(const half8*)&smem[cur][2][row * 64 + sfw * 16];
                    blv[q] = *(const half8*)&smem[cur][3][row * 64 + sfw * 16];
                }
            }
            #pragma unroll
            for (int mi = 0; mi < 4; ++mi)
                #pragma unroll
                for (int ni = 0; ni < 4; ++ni) {
                    acc[mi][ni] = __builtin_amdgcn_mfma_f32_16x16x32_f16(ah[mi], bhv[ni], acc[mi][ni], 0, 0, 0);
                    acc[mi][ni] = __builtin_amdgcn_mfma_f32_16x16x32_f16(ah[mi], blv[ni], acc[mi][ni], 0, 0, 0);
                    acc[mi][ni] = __builtin_amdgcn_mfma_f32_16x16x32_f16(al[mi], bhv[ni], acc[mi][ni], 0, 0, 0);
                }
            __syncthreads();
        }

        // fold this 128-col tile into per-lane top-3/max state (d^2 domain)
        #pragma unroll
        for (int ni = 0; ni < 4; ++ni) {
            float sc = sq[cb + wn * 64 + ni * 16 + (l & 15)];
            #pragma unroll
            for (int mi = 0; mi < 4; ++mi)
                #pragma unroll
                for (int j = 0; j < 4; ++j) {
                    int idx = mi * 4 + j;
                    float d2v = fmaf(-2.0f, acc[mi][ni][j], sr[idx] + sc);
                    float lo0 = fminf(st0[idx], d2v), hi0 = fmaxf(st0[idx], d2v);
                    st0[idx] = lo0;
                    float lo1 = fminf(st1[idx], hi0), hi1 = fmaxf(st1[idx], hi0);
                    st1[idx] = lo1;
                    st2[idx] = fminf(st2[idx], hi1);
                    stx[idx] = fmaxf(stx[idx], d2v);
                }
        }
    }
#undef STAGE

    // merge across the 16 lanes (same rows, different cols)
    #pragma unroll
    for (int s = 1; s < 16; s <<= 1) {
        #pragma unroll
        for (int i = 0; i < 16; ++i) {
            float b0 = __shfl_xor(st0[i], s);
            float b1 = __shfl_xor(st1[i], s);
            float b2 = __shfl_xor(st2[i], s);
            float bm = __shfl_xor(stx[i], s);
            float n0 = fminf(st0[i], b0);
            float n1 = fminf(fmaxf(st0[i], b0), fminf(st1[i], b1));
            float n2 = fminf(fminf(st2[i], b2),
                             fminf(fmaxf(st0[i], b1), fmaxf(st1[i], b0)));
            st0[i] = n0; st1[i] = n1; st2[i] = n2; stx[i] = fmaxf(stx[i], bm);
        }
    }
    if ((l & 15) == 0) {
        const int g = l >> 4;
        const int p = strip * 2 + wn;
        #pragma unroll
        for (int mi = 0; mi < 4; ++mi)
            #pragma unroll
            for (int j = 0; j < 4; ++j) {
                int row = r0 + wm * 64 + mi * 16 + g * 4 + j;
                float4 v = make_float4(st0[mi * 4 + j], st1[mi * 4 + j],
                                       st2[mi * 4 + j], stx[mi * 4 + j]);
                *(float4*)&part[((size_t)row * 8 + p) * 4] = v;
            }
    }
}

// combine: merge the 8 partial triples per row, then sqrt + prediction
__global__ __launch_bounds__(256) void combine_kernel(const float* __restrict__ part,
                                                      float* __restrict__ out) {
    const int row = blockIdx.x * 256 + threadIdx.x;
    float m0 = 3.402823466e+38f, m1 = 3.402823466e+38f, m2 = 3.402823466e+38f;
    float mx = 0.0f;
    #pragma unroll
    for (int p = 0; p < 8; ++p) {
        float4 t = *(const float4*)&part[((size_t)row * 8 + p) * 4];
        float n0 = fminf(m0, t.x);
        float n1 = fminf(fmaxf(m0, t.x), fminf(m1, t.y));
        float n2 = fminf(fminf(m2, t.z), fminf(fmaxf(m0, t.y), fmaxf(m1, t.x)));
        m0 = n0; m1 = n1; m2 = n2; mx = fmaxf(mx, t.w);
    }
    float d1 = sqrtf(fmaxf(m1, 0.0f) + 1e-12f);
    float d2 = sqrtf(fmaxf(m2, 0.0f) + 1e-12f);
    float dm = sqrtf(fmaxf(mx, 0.0f) + 1e-12f);
    out[row] = (d1 / d2 < 0.6f) ? 2.0f / (1.0f + expf(d1))
                                : 2.0f / (1.0f + 2.0f * expf(dm));
}

// ============================================================================
// Path B (fallback, fp32 VALU — the verified round-1 kernels) if ws too small
// ============================================================================

__global__ __launch_bounds__(256) void sq_kernel(const float* __restrict__ x,
                                                 float* __restrict__ sq) {
    int wid = threadIdx.x >> 6;
    int lane = threadIdx.x & 63;
    int row = blockIdx.x * 4 + wid;
    const float* f = x + (size_t)row * CDIM;
    float4 v0 = *(const float4*)(f + lane * 8);
    float4 v1 = *(const float4*)(f + lane * 8 + 4);
    float s = v0.x*v0.x + v0.y*v0.y + v0.z*v0.z + v0.w*v0.w
            + v1.x*v1.x + v1.y*v1.y + v1.z*v1.z + v1.w*v1.w;
    #pragma unroll
    for (int o = 32; o > 0; o >>= 1) s += __shfl_xor(s, o);
    if (lane == 0) sq[row] = s;
}

__global__ __launch_bounds__(256, 2) void fcm_kernel(const float* __restrict__ x,
                                                     const float* __restrict__ sq,
                                                     float* __restrict__ out) {
    __shared__ __align__(16) float a_s[32][36];
    __shared__ __align__(16) float b_s[32][260];
    const int tid = threadIdx.x;
    const int ty = tid >> 6;
    const int tx = tid & 63;
    const int brow = blockIdx.x * 32;
    const int batch = brow >> 12;
    const int irow = brow & (NPTS - 1);
    const float* f = x + (size_t)batch * NPTS * CDIM;
    const float* sqb = sq + batch * NPTS;

    float srr[8];
    #pragma unroll
    for (int r = 0; r < 8; ++r) srr[r] = sqb[irow + ty * 8 + r];
    float m0[8], m1[8], m2[8], mx[8];
    #pragma unroll
    for (int r = 0; r < 8; ++r) {
        m0[r] = 3.402823466e+38f; m1[r] = 3.402823466e+38f;
        m2[r] = 3.402823466e+38f; mx[r] = 0.0f;
    }
    for (int ct = 0; ct < NPTS / 256; ++ct) {
        const int cbase = ct * 256;
        float acc[8][4];
        #pragma unroll
        for (int r = 0; r < 8; ++r)
            #pragma unroll
            for (int q = 0; q < 4; ++q) acc[r][q] = 0.0f;
        for (int kc = 0; kc < CDIM; kc += 32) {
            {
                int row = tid >> 3, l8 = tid & 7;
                float4 v = *(const float4*)(f + (size_t)(irow + row) * CDIM + kc + l8 * 4);
                a_s[l8 * 4 + 0][row] = v.x; a_s[l8 * 4 + 1][row] = v.y;
                a_s[l8 * 4 + 2][row] = v.z; a_s[l8 * 4 + 3][row] = v.w;
            }
            {
                int colb = tid >> 2, l4 = tid & 3;
                #pragma unroll
                for (int it = 0; it < 4; ++it) {
                    int col = colb + 64 * it;
                    const float* p = f + (size_t)(cbase + col) * CDIM + kc + l4 * 8;
                    float4 v0 = *(const float4*)p;
                    float4 v1 = *(const float4*)(p + 4);
                    b_s[l4 * 8 + 0][col] = v0.x; b_s[l4 * 8 + 1][col] = v0.y;
                    b_s[l4 * 8 + 2][col] = v0.z; b_s[l4 * 8 + 3][col] = v0.w;
                    b_s[l4 * 8 + 4][col] = v1.x; b_s[l4 * 8 + 5][col] = v1.y;
                    b_s[l4 * 8 + 6][col] = v1.z; b_s[l4 * 8 + 7][col] = v1.w;
                }
            }
            __syncthreads();
            #pragma unroll
            for (int k = 0; k < 32; ++k) {
                float a0[8], b0[4];
                *(float4*)&a0[0] = *(const float4*)&a_s[k][ty * 8];
                *(float4*)&a0[4] = *(const float4*)&a_s[k][ty * 8 + 4];
                *(float4*)&b0[0] = *(const float4*)&b_s[k][tx * 4];
                #pragma unroll
                for (int r = 0; r < 8; ++r)
                    #pragma unroll
                    for (int q = 0; q < 4; ++q)
                        acc[r][q] = fmaf(a0[r], b0[q], acc[r][q]);
            }
            __syncthreads();
        }
        #pragma unroll
        for (int q = 0; q < 4; ++q) {
            float sc = sqb[cbase + tx * 4 + q];
            #pragma unroll
            for (int r = 0; r < 8; ++r) {
                float d2v = fmaf(-2.0f, acc[r][q], srr[r] + sc);
                d2v = fmaxf(d2v, 0.0f);
                float d = sqrtf(d2v + 1e-12f);
                float lo = fminf(m0[r], d), hi = fmaxf(m0[r], d);
                m0[r] = lo;
                float lo1 = fminf(m1[r], hi), hi1 = fmaxf(m1[r], hi);
                m1[r] = lo1;
                m2[r] = fminf(m2[r], hi1);
                mx[r] = fmaxf(mx[r], d);
            }
        }
    }
    #pragma unroll
    for (int s = 1; s < 64; s <<= 1) {
        #pragma unroll
        for (int r = 0; r < 8; ++r) {
            float b0v = __shfl_xor(m0[r], s);
            float b1v = __shfl_xor(m1[r], s);
            float b2v = __shfl_xor(m2[r], s);
            float bmv = __shfl_xor(mx[r], s);
            float n0 = fminf(m0[r], b0v);
            float n1 = fminf(fmaxf(m0[r], b0v), fminf(m1[r], b1v));
            float n2 = fminf(fminf(m2[r], b2v),
                             fminf(fmaxf(m0[r], b1v), fmaxf(m1[r], b0v)));
            m0[r] = n0; m1[r] = n1; m2[r] = n2; mx[r] = fmaxf(mx[r], bmv);
        }
    }
    if (tx == 0) {
        #pragma unroll
        for (int r = 0; r < 8; ++r) {
            int grow = brow + ty * 8 + r;
            float d1 = m1[r], d2nd = m2[r], dmaxv = mx[r];
            float pred = (d1 / d2nd < 0.6f) ? 2.0f / (1.0f + expf(d1))
                                            : 2.0f / (1.0f + 2.0f * expf(dmaxv));
            out[grow] = pred;
        }
    }
}

extern "C" void kernel_launch(void* const* d_in, const int* in_sizes, int n_in,
                              void* d_out, int out_size, void* d_ws, size_t ws_size,
                              hipStream_t stream) {
    const float* x = (const float*)d_in[0];
    float* out = (float*)d_out;

    const size_t plane = (size_t)NROWS * CDIM * sizeof(half_t);  // 16,777,216
    const size_t need = 2 * plane + NROWS * sizeof(float) + (size_t)NROWS * 8 * 16;

    if (ws_size >= need) {
        half_t* hi = (half_t*)d_ws;
        half_t* lo = (half_t*)((char*)d_ws + plane);
        float* sq = (float*)((char*)d_ws + 2 * plane);
        float* part = (float*)((char*)d_ws + 2 * plane + NROWS * sizeof(float));
        prep_kernel<<<dim3(NROWS / 4), dim3(256), 0, stream>>>(x, hi, lo, sq);
        fcm_mfma<<<dim3(512), dim3(256), 0, stream>>>(hi, lo, sq, part);
        combine_kernel<<<dim3(NROWS / 256), dim3(256), 0, stream>>>(part, out);
    } else {
        float* sqw = (float*)d_ws;
        sq_kernel<<<dim3(4096), dim3(256), 0, stream>>>(x, sqw);
        fcm_kernel<<<dim3(512), dim3(256), 0, stream>>>(x, sqw, out);
    }
}

// Round 3
// 119.624 us; speedup vs baseline: 8.6440x; 1.8465x over previous
//
#include <hip/hip_runtime.h>
#include <math.h>

#define NPTS 4096
#define CDIM 512
#define NROWS 16384

typedef _Float16 half_t;
typedef _Float16 half8 __attribute__((ext_vector_type(8)));
typedef float f32x4 __attribute__((ext_vector_type(4)));

__device__ inline void gl_lds16(const void* g, void* l) {
    __builtin_amdgcn_global_load_lds(
        (const __attribute__((address_space(1))) uint32_t*)g,
        (__attribute__((address_space(3))) uint32_t*)l, 16, 0, 0);
}

// ============================================================================
// Path A (1-pass f16 MFMA): prep -> fcm_mfma -> combine
// Image layout: row stride 1024 B; per row 8 Kblocks of 64 ch (128 B);
// each Kblock = 8 slots x 16 B, slot s (ch [s*8,s*8+8)) stored at s^(row&7).
// ============================================================================

__global__ __launch_bounds__(256) void prep_kernel(const float* __restrict__ x,
                                                   half_t* __restrict__ hi,
                                                   float* __restrict__ sq) {
    const int wv = threadIdx.x >> 6, l = threadIdx.x & 63;
    const int row = blockIdx.x * 4 + wv;
    const float* f = x + (size_t)row * CDIM;
    float4 v0 = *(const float4*)(f + l * 8);
    float4 v1 = *(const float4*)(f + l * 8 + 4);
    float xs[8] = {v0.x, v0.y, v0.z, v0.w, v1.x, v1.y, v1.z, v1.w};
    half8 h;
    float s = 0.0f;
    #pragma unroll
    for (int i = 0; i < 8; ++i) {
        float v = xs[i];
        s = fmaf(v, v, s);
        h[i] = (half_t)v;
    }
    #pragma unroll
    for (int o = 32; o > 0; o >>= 1) s += __shfl_xor(s, o);
    const int kb = l >> 3;
    const int pos = (l & 7) ^ (row & 7);
    *(half8*)(hi + (size_t)row * CDIM + kb * 64 + pos * 8) = h;
    if (l == 0) sq[row] = s;
}

// main: 128x128 tile/block, 4 waves (2x2, 64x64 each), BK=64, double-buffered
// LDS via global_load_lds (linear dest; swizzle pre-baked in the global image).
// One f16 MFMA pass; top-3-min/max folded per 128-col tile in d^2 domain.
__global__ __launch_bounds__(256, 2) void fcm_mfma(const half_t* __restrict__ hi,
                                                   const float* __restrict__ sq,
                                                   float* __restrict__ part) {
    __shared__ __align__(16) char smem[2][2][16384];  // [buf][A,B][128 rows x 128 B]
    const int tid = threadIdx.x, wv = tid >> 6, l = tid & 63;
    const int wm = wv >> 1, wn = wv & 1;
    const int bid = blockIdx.x;
    const int rb = bid & 127, strip = bid >> 7;       // 128 row-blocks x 4 strips
    const int r0 = rb * 128;
    const int batch = r0 >> 12;
    const int cflat0 = (batch << 12) + strip * 1024;
    const char* base = (const char*)hi;

    float sr[16];
    #pragma unroll
    for (int mi = 0; mi < 4; ++mi)
        #pragma unroll
        for (int j = 0; j < 4; ++j)
            sr[mi * 4 + j] = sq[r0 + wm * 64 + mi * 16 + (l >> 4) * 4 + j];

    float st0[16], st1[16], st2[16], stx[16];         // d^2 domain
    #pragma unroll
    for (int i = 0; i < 16; ++i) {
        st0[i] = 3.402823466e+38f; st1[i] = 3.402823466e+38f;
        st2[i] = 3.402823466e+38f; stx[i] = 0.0f;
    }

    // fragment byte offsets within A/B LDS buffers (constant per thread)
    int aoff[4][2], boff[4][2];
    #pragma unroll
    for (int q = 0; q < 4; ++q)
        #pragma unroll
        for (int kc = 0; kc < 2; ++kc) {
            int rowa = wm * 64 + q * 16 + (l & 15);
            aoff[q][kc] = rowa * 128 + ((((l >> 4) + kc * 4) ^ (rowa & 7)) * 16);
            int rowb = wn * 64 + q * 16 + (l & 15);
            boff[q][kc] = rowb * 128 + ((((l >> 4) + kc * 4) ^ (rowb & 7)) * 16);
        }

    // stage src row/inner (constant per thread per issue)
    int srow[4], sin[4];
    #pragma unroll
    for (int i = 0; i < 4; ++i) {
        int dl = i * 4096 + wv * 1024 + l * 16;
        srow[i] = dl >> 7;
        sin[i] = dl & 127;
    }

#define STAGE(buf, ctv, ksv) do {                                              \
        const int cb_ = cflat0 + (ctv) * 128;                                  \
        _Pragma("unroll")                                                      \
        for (int i_ = 0; i_ < 4; ++i_) {                                       \
            const int db_ = i_ * 4096 + wv * 1024;                             \
            gl_lds16(base + (size_t)(r0 + srow[i_]) * 1024 + (ksv) * 128 + sin[i_], \
                     &smem[buf][0][db_]);                                      \
            gl_lds16(base + (size_t)(cb_ + srow[i_]) * 1024 + (ksv) * 128 + sin[i_], \
                     &smem[buf][1][db_]);                                      \
        } } while (0)

    STAGE(0, 0, 0);
    __syncthreads();

    for (int ct = 0; ct < 8; ++ct) {
        f32x4 acc[4][4];
        #pragma unroll
        for (int mi = 0; mi < 4; ++mi)
            #pragma unroll
            for (int ni = 0; ni < 4; ++ni)
                #pragma unroll
                for (int j = 0; j < 4; ++j) acc[mi][ni][j] = 0.0f;

        #pragma unroll
        for (int ks = 0; ks < 8; ++ks) {
            const int cur = ks & 1;
            if (ks < 7) STAGE(cur ^ 1, ct, ks + 1);
            else if (ct < 7) STAGE(cur ^ 1, ct + 1, 0);
            #pragma unroll
            for (int kc = 0; kc < 2; ++kc) {
                half8 af[4], bf[4];
                #pragma unroll
                for (int q = 0; q < 4; ++q) {
                    af[q] = *(const half8*)&smem[cur][0][aoff[q][kc]];
                    bf[q] = *(const half8*)&smem[cur][1][boff[q][kc]];
                }
                #pragma unroll
                for (int mi = 0; mi < 4; ++mi)
                    #pragma unroll
                    for (int ni = 0; ni < 4; ++ni)
                        acc[mi][ni] = __builtin_amdgcn_mfma_f32_16x16x32_f16(
                            af[mi], bf[ni], acc[mi][ni], 0, 0, 0);
            }
            __syncthreads();
        }

        // fold this 128-col tile (d^2 domain)
        const int cb = cflat0 + ct * 128;
        #pragma unroll
        for (int ni = 0; ni < 4; ++ni) {
            float sc = sq[cb + wn * 64 + ni * 16 + (l & 15)];
            #pragma unroll
            for (int mi = 0; mi < 4; ++mi)
                #pragma unroll
                for (int j = 0; j < 4; ++j) {
                    int idx = mi * 4 + j;
                    float d2v = fmaf(-2.0f, acc[mi][ni][j], sr[idx] + sc);
                    float lo0 = fminf(st0[idx], d2v), hi0 = fmaxf(st0[idx], d2v);
                    st0[idx] = lo0;
                    float lo1 = fminf(st1[idx], hi0), hi1 = fmaxf(st1[idx], hi0);
                    st1[idx] = lo1;
                    st2[idx] = fminf(st2[idx], hi1);
                    stx[idx] = fmaxf(stx[idx], d2v);
                }
        }
    }
#undef STAGE

    // merge across the 16 lanes of each row-group (cols differ, rows shared)
    #pragma unroll
    for (int s = 1; s < 16; s <<= 1) {
        #pragma unroll
        for (int i = 0; i < 16; ++i) {
            float b0 = __shfl_xor(st0[i], s);
            float b1 = __shfl_xor(st1[i], s);
            float b2 = __shfl_xor(st2[i], s);
            float bm = __shfl_xor(stx[i], s);
            float n0 = fminf(st0[i], b0);
            float n1 = fminf(fmaxf(st0[i], b0), fminf(st1[i], b1));
            float n2 = fminf(fminf(st2[i], b2),
                             fminf(fmaxf(st0[i], b1), fmaxf(st1[i], b0)));
            st0[i] = n0; st1[i] = n1; st2[i] = n2; stx[i] = fmaxf(stx[i], bm);
        }
    }
    if ((l & 15) == 0) {
        const int g = l >> 4;
        const int p = strip * 2 + wn;
        #pragma unroll
        for (int mi = 0; mi < 4; ++mi)
            #pragma unroll
            for (int j = 0; j < 4; ++j) {
                int row = r0 + wm * 64 + mi * 16 + g * 4 + j;
                float4 v = make_float4(st0[mi * 4 + j], st1[mi * 4 + j],
                                       st2[mi * 4 + j], stx[mi * 4 + j]);
                *(float4*)&part[((size_t)row * 8 + p) * 4] = v;
            }
    }
}

// combine: merge 8 partial triples per row, then sqrt + prediction
__global__ __launch_bounds__(256) void combine_kernel(const float* __restrict__ part,
                                                      float* __restrict__ out) {
    const int row = blockIdx.x * 256 + threadIdx.x;
    float m0 = 3.402823466e+38f, m1 = 3.402823466e+38f, m2 = 3.402823466e+38f;
    float mx = 0.0f;
    #pragma unroll
    for (int p = 0; p < 8; ++p) {
        float4 t = *(const float4*)&part[((size_t)row * 8 + p) * 4];
        float n0 = fminf(m0, t.x);
        float n1 = fminf(fmaxf(m0, t.x), fminf(m1, t.y));
        float n2 = fminf(fminf(m2, t.z), fminf(fmaxf(m0, t.y), fmaxf(m1, t.x)));
        m0 = n0; m1 = n1; m2 = n2; mx = fmaxf(mx, t.w);
    }
    float d1 = sqrtf(fmaxf(m1, 0.0f) + 1e-12f);
    float d2 = sqrtf(fmaxf(m2, 0.0f) + 1e-12f);
    float dm = sqrtf(fmaxf(mx, 0.0f) + 1e-12f);
    out[row] = (d1 / d2 < 0.6f) ? 2.0f / (1.0f + expf(d1))
                                : 2.0f / (1.0f + 2.0f * expf(dm));
}

// ============================================================================
// Path B (fallback, fp32 VALU) if ws too small
// ============================================================================

__global__ __launch_bounds__(256) void sq_kernel(const float* __restrict__ x,
                                                 float* __restrict__ sq) {
    int wid = threadIdx.x >> 6;
    int lane = threadIdx.x & 63;
    int row = blockIdx.x * 4 + wid;
    const float* f = x + (size_t)row * CDIM;
    float4 v0 = *(const float4*)(f + lane * 8);
    float4 v1 = *(const float4*)(f + lane * 8 + 4);
    float s = v0.x*v0.x + v0.y*v0.y + v0.z*v0.z + v0.w*v0.w
            + v1.x*v1.x + v1.y*v1.y + v1.z*v1.z + v1.w*v1.w;
    #pragma unroll
    for (int o = 32; o > 0; o >>= 1) s += __shfl_xor(s, o);
    if (lane == 0) sq[row] = s;
}

__global__ __launch_bounds__(256, 2) void fcm_kernel(const float* __restrict__ x,
                                                     const float* __restrict__ sq,
                                                     float* __restrict__ out) {
    __shared__ __align__(16) float a_s[32][36];
    __shared__ __align__(16) float b_s[32][260];
    const int tid = threadIdx.x;
    const int ty = tid >> 6;
    const int tx = tid & 63;
    const int brow = blockIdx.x * 32;
    const int batch = brow >> 12;
    const int irow = brow & (NPTS - 1);
    const float* f = x + (size_t)batch * NPTS * CDIM;
    const float* sqb = sq + batch * NPTS;

    float srr[8];
    #pragma unroll
    for (int r = 0; r < 8; ++r) srr[r] = sqb[irow + ty * 8 + r];
    float m0[8], m1[8], m2[8], mx[8];
    #pragma unroll
    for (int r = 0; r < 8; ++r) {
        m0[r] = 3.402823466e+38f; m1[r] = 3.402823466e+38f;
        m2[r] = 3.402823466e+38f; mx[r] = 0.0f;
    }
    for (int ct = 0; ct < NPTS / 256; ++ct) {
        const int cbase = ct * 256;
        float acc[8][4];
        #pragma unroll
        for (int r = 0; r < 8; ++r)
            #pragma unroll
            for (int q = 0; q < 4; ++q) acc[r][q] = 0.0f;
        for (int kc = 0; kc < CDIM; kc += 32) {
            {
                int row = tid >> 3, l8 = tid & 7;
                float4 v = *(const float4*)(f + (size_t)(irow + row) * CDIM + kc + l8 * 4);
                a_s[l8 * 4 + 0][row] = v.x; a_s[l8 * 4 + 1][row] = v.y;
                a_s[l8 * 4 + 2][row] = v.z; a_s[l8 * 4 + 3][row] = v.w;
            }
            {
                int colb = tid >> 2, l4 = tid & 3;
                #pragma unroll
                for (int it = 0; it < 4; ++it) {
                    int col = colb + 64 * it;
                    const float* p = f + (size_t)(cbase + col) * CDIM + kc + l4 * 8;
                    float4 v0 = *(const float4*)p;
                    float4 v1 = *(const float4*)(p + 4);
                    b_s[l4 * 8 + 0][col] = v0.x; b_s[l4 * 8 + 1][col] = v0.y;
                    b_s[l4 * 8 + 2][col] = v0.z; b_s[l4 * 8 + 3][col] = v0.w;
                    b_s[l4 * 8 + 4][col] = v1.x; b_s[l4 * 8 + 5][col] = v1.y;
                    b_s[l4 * 8 + 6][col] = v1.z; b_s[l4 * 8 + 7][col] = v1.w;
                }
            }
            __syncthreads();
            #pragma unroll
            for (int k = 0; k < 32; ++k) {
                float a0[8], b0[4];
                *(float4*)&a0[0] = *(const float4*)&a_s[k][ty * 8];
                *(float4*)&a0[4] = *(const float4*)&a_s[k][ty * 8 + 4];
                *(float4*)&b0[0] = *(const float4*)&b_s[k][tx * 4];
                #pragma unroll
                for (int r = 0; r < 8; ++r)
                    #pragma unroll
                    for (int q = 0; q < 4; ++q)
                        acc[r][q] = fmaf(a0[r], b0[q], acc[r][q]);
            }
            __syncthreads();
        }
        #pragma unroll
        for (int q = 0; q < 4; ++q) {
            float sc = sqb[cbase + tx * 4 + q];
            #pragma unroll
            for (int r = 0; r < 8; ++r) {
                float d2v = fmaf(-2.0f, acc[r][q], srr[r] + sc);
                d2v = fmaxf(d2v, 0.0f);
                float d = sqrtf(d2v + 1e-12f);
                float lo = fminf(m0[r], d), hi = fmaxf(m0[r], d);
                m0[r] = lo;
                float lo1 = fminf(m1[r], hi), hi1 = fmaxf(m1[r], hi);
                m1[r] = lo1;
                m2[r] = fminf(m2[r], hi1);
                mx[r] = fmaxf(mx[r], d);
            }
        }
    }
    #pragma unroll
    for (int s = 1; s < 64; s <<= 1) {
        #pragma unroll
        for (int r = 0; r < 8; ++r) {
            float b0v = __shfl_xor(m0[r], s);
            float b1v = __shfl_xor(m1[r], s);
            float b2v = __shfl_xor(m2[r], s);
            float bmv = __shfl_xor(mx[r], s);
            float n0 = fminf(m0[r], b0v);
            float n1 = fminf(fmaxf(m0[r], b0v), fminf(m1[r], b1v));
            float n2 = fminf(fminf(m2[r], b2v),
                             fminf(fmaxf(m0[r], b1v), fmaxf(m1[r], b0v)));
            m0[r] = n0; m1[r] = n1; m2[r] = n2; mx[r] = fmaxf(mx[r], bmv);
        }
    }
    if (tx == 0) {
        #pragma unroll
        for (int r = 0; r < 8; ++r) {
            int grow = brow + ty * 8 + r;
            float d1 = m1[r], d2nd = m2[r], dmaxv = mx[r];
            float pred = (d1 / d2nd < 0.6f) ? 2.0f / (1.0f + expf(d1))
                                            : 2.0f / (1.0f + 2.0f * expf(dmaxv));
            out[grow] = pred;
        }
    }
}

extern "C" void kernel_launch(void* const* d_in, const int* in_sizes, int n_in,
                              void* d_out, int out_size, void* d_ws, size_t ws_size,
                              hipStream_t stream) {
    const float* x = (const float*)d_in[0];
    float* out = (float*)d_out;

    const size_t plane = (size_t)NROWS * CDIM * sizeof(half_t);  // 16 MB
    const size_t need = plane + NROWS * sizeof(float) + (size_t)NROWS * 8 * 16;

    if (ws_size >= need) {
        half_t* hi = (half_t*)d_ws;
        float* sq = (float*)((char*)d_ws + plane);
        float* part = (float*)((char*)d_ws + plane + NROWS * sizeof(float));
        prep_kernel<<<dim3(NROWS / 4), dim3(256), 0, stream>>>(x, hi, sq);
        fcm_mfma<<<dim3(512), dim3(256), 0, stream>>>(hi, sq, part);
        combine_kernel<<<dim3(NROWS / 256), dim3(256), 0, stream>>>(part, out);
    } else {
        float* sqw = (float*)d_ws;
        sq_kernel<<<dim3(4096), dim3(256), 0, stream>>>(x, sqw);
        fcm_kernel<<<dim3(512), dim3(256), 0, stream>>>(x, sqw, out);
    }
}

// Round 4
// 98.347 us; speedup vs baseline: 10.5141x; 1.2164x over previous
//
#include <hip/hip_runtime.h>
#include <math.h>

#define NPTS 4096
#define CDIM 512
#define NROWS 16384
#define NTILES 528   // 32*33/2 per batch

typedef _Float16 half_t;
typedef _Float16 half8 __attribute__((ext_vector_type(8)));
typedef float f32x4 __attribute__((ext_vector_type(4)));

__device__ inline void gl_lds16(const void* g, void* l) {
    __builtin_amdgcn_global_load_lds(
        (const __attribute__((address_space(1))) uint32_t*)g,
        (__attribute__((address_space(3))) uint32_t*)l, 16, 0, 0);
}

__device__ __forceinline__ int tri_start(int i) {  // tiles before row i
    return 32 * i - (i * (i - 1)) / 2;
}

// ============================================================================
// Path A: prep -> fcm_sym (triangular tiles, both-side fold) -> combine
// Image layout: row stride 1024 B; 8 Kblocks of 64 ch (128 B); slot s at
// s^(row&7) within the Kblock (pre-baked LDS swizzle).
// ============================================================================

__global__ __launch_bounds__(256) void prep_kernel(const float* __restrict__ x,
                                                   half_t* __restrict__ hi,
                                                   float* __restrict__ sq) {
    const int wv = threadIdx.x >> 6, l = threadIdx.x & 63;
    const int row = blockIdx.x * 4 + wv;
    const float* f = x + (size_t)row * CDIM;
    float4 v0 = *(const float4*)(f + l * 8);
    float4 v1 = *(const float4*)(f + l * 8 + 4);
    float xs[8] = {v0.x, v0.y, v0.z, v0.w, v1.x, v1.y, v1.z, v1.w};
    half8 h;
    float s = 0.0f;
    #pragma unroll
    for (int i = 0; i < 8; ++i) {
        float v = xs[i];
        s = fmaf(v, v, s);
        h[i] = (half_t)v;
    }
    #pragma unroll
    for (int o = 32; o > 0; o >>= 1) s += __shfl_xor(s, o);
    const int kb = l >> 3;
    const int pos = (l & 7) ^ (row & 7);
    *(half8*)(hi + (size_t)row * CDIM + kb * 64 + pos * 8) = h;
    if (l == 0) sq[row] = s;
}

// One block per triangular tile (I,J), J>=I, per batch. 128x128 tile, 4 waves
// (2x2, 64x64 each), BK=64, double-buffered LDS via global_load_lds.
// Epilogue: row-side fold (rows of I over cols of J) -> slot 2J+wn;
// col-side fold (rows of J over rows of I; skipped if I==J) -> slot 2I+wm.
// part layout: [slot][row] float4 (m0,m1,m2,max) in d^2 domain.
__global__ __launch_bounds__(256, 2) void fcm_sym(const half_t* __restrict__ hi,
                                                  const float* __restrict__ sq,
                                                  float4* __restrict__ part4) {
    __shared__ __align__(16) char smem[2][2][16384];
    const int tid = threadIdx.x, wv = tid >> 6, l = tid & 63;
    const int wm = wv >> 1, wn = wv & 1;
    const int bid = blockIdx.x;
    const int batch = bid / NTILES;
    const int t = bid - batch * NTILES;
    int I = (int)((65.0f - sqrtf(4225.0f - 8.0f * (float)t)) * 0.5f);
    while (tri_start(I + 1) <= t) ++I;
    while (tri_start(I) > t) --I;
    const int J = I + (t - tri_start(I));
    const int r0 = (batch << 12) + I * 128;
    const int c0 = (batch << 12) + J * 128;
    const char* base = (const char*)hi;

    float sr[16];
    #pragma unroll
    for (int mi = 0; mi < 4; ++mi)
        #pragma unroll
        for (int j = 0; j < 4; ++j)
            sr[mi * 4 + j] = sq[r0 + wm * 64 + mi * 16 + (l >> 4) * 4 + j];
    float scn[4];
    #pragma unroll
    for (int ni = 0; ni < 4; ++ni)
        scn[ni] = sq[c0 + wn * 64 + ni * 16 + (l & 15)];

    // fragment byte offsets within A/B LDS buffers (constant per thread)
    int aoff[4][2], boff[4][2];
    #pragma unroll
    for (int q = 0; q < 4; ++q)
        #pragma unroll
        for (int kc = 0; kc < 2; ++kc) {
            int rowa = wm * 64 + q * 16 + (l & 15);
            aoff[q][kc] = rowa * 128 + ((((l >> 4) + kc * 4) ^ (rowa & 7)) * 16);
            int rowb = wn * 64 + q * 16 + (l & 15);
            boff[q][kc] = rowb * 128 + ((((l >> 4) + kc * 4) ^ (rowb & 7)) * 16);
        }

    int srow[4], sin[4];
    #pragma unroll
    for (int i = 0; i < 4; ++i) {
        int dl = i * 4096 + wv * 1024 + l * 16;
        srow[i] = dl >> 7;
        sin[i] = dl & 127;
    }

#define STAGE(buf, ksv) do {                                                   \
        _Pragma("unroll")                                                      \
        for (int i_ = 0; i_ < 4; ++i_) {                                       \
            const int db_ = i_ * 4096 + wv * 1024;                             \
            gl_lds16(base + (size_t)(r0 + srow[i_]) * 1024 + (ksv) * 128 + sin[i_], \
                     &smem[buf][0][db_]);                                      \
            gl_lds16(base + (size_t)(c0 + srow[i_]) * 1024 + (ksv) * 128 + sin[i_], \
                     &smem[buf][1][db_]);                                      \
        } } while (0)

    f32x4 acc[4][4];
    #pragma unroll
    for (int mi = 0; mi < 4; ++mi)
        #pragma unroll
        for (int ni = 0; ni < 4; ++ni)
            #pragma unroll
            for (int j = 0; j < 4; ++j) acc[mi][ni][j] = 0.0f;

    STAGE(0, 0);
    __syncthreads();
    #pragma unroll
    for (int ks = 0; ks < 8; ++ks) {
        const int cur = ks & 1;
        if (ks < 7) STAGE(cur ^ 1, ks + 1);
        #pragma unroll
        for (int kc = 0; kc < 2; ++kc) {
            half8 af[4], bf[4];
            #pragma unroll
            for (int q = 0; q < 4; ++q) {
                af[q] = *(const half8*)&smem[cur][0][aoff[q][kc]];
                bf[q] = *(const half8*)&smem[cur][1][boff[q][kc]];
            }
            #pragma unroll
            for (int mi = 0; mi < 4; ++mi)
                #pragma unroll
                for (int ni = 0; ni < 4; ++ni)
                    acc[mi][ni] = __builtin_amdgcn_mfma_f32_16x16x32_f16(
                        af[mi], bf[ni], acc[mi][ni], 0, 0, 0);
        }
        __syncthreads();
    }
#undef STAGE

    // ---- row-side fold: rows of block I over this tile's 128 cols ----
    float st0[16], st1[16], st2[16], stx[16];
    #pragma unroll
    for (int i = 0; i < 16; ++i) {
        st0[i] = 3.402823466e+38f; st1[i] = 3.402823466e+38f;
        st2[i] = 3.402823466e+38f; stx[i] = 0.0f;
    }
    #pragma unroll
    for (int ni = 0; ni < 4; ++ni) {
        float sc = scn[ni];
        #pragma unroll
        for (int mi = 0; mi < 4; ++mi)
            #pragma unroll
            for (int j = 0; j < 4; ++j) {
                int idx = mi * 4 + j;
                float d2v = fmaf(-2.0f, acc[mi][ni][j], sr[idx] + sc);
                float lo0 = fminf(st0[idx], d2v), hi0 = fmaxf(st0[idx], d2v);
                st0[idx] = lo0;
                float lo1 = fminf(st1[idx], hi0), hi1 = fmaxf(st1[idx], hi0);
                st1[idx] = lo1;
                st2[idx] = fminf(st2[idx], hi1);
                stx[idx] = fmaxf(stx[idx], d2v);
            }
    }
    #pragma unroll
    for (int s = 1; s < 16; s <<= 1) {
        #pragma unroll
        for (int i = 0; i < 16; ++i) {
            float b0 = __shfl_xor(st0[i], s);
            float b1 = __shfl_xor(st1[i], s);
            float b2 = __shfl_xor(st2[i], s);
            float bm = __shfl_xor(stx[i], s);
            float n0 = fminf(st0[i], b0);
            float n1 = fminf(fmaxf(st0[i], b0), fminf(st1[i], b1));
            float n2 = fminf(fminf(st2[i], b2),
                             fminf(fmaxf(st0[i], b1), fmaxf(st1[i], b0)));
            st0[i] = n0; st1[i] = n1; st2[i] = n2; stx[i] = fmaxf(stx[i], bm);
        }
    }
    if ((l & 15) == 0) {
        const int g = l >> 4;
        const int slot = 2 * J + wn;
        #pragma unroll
        for (int mi = 0; mi < 4; ++mi)
            #pragma unroll
            for (int j = 0; j < 4; ++j) {
                int row = r0 + wm * 64 + mi * 16 + g * 4 + j;
                part4[(size_t)slot * NROWS + row] =
                    make_float4(st0[mi * 4 + j], st1[mi * 4 + j],
                                st2[mi * 4 + j], stx[mi * 4 + j]);
            }
    }

    // ---- col-side fold: rows of block J over this tile's 128 rows ----
    if (J > I) {
        float c0s[4], c1s[4], c2s[4], cxs[4];
        #pragma unroll
        for (int ni = 0; ni < 4; ++ni) {
            c0s[ni] = 3.402823466e+38f; c1s[ni] = 3.402823466e+38f;
            c2s[ni] = 3.402823466e+38f; cxs[ni] = 0.0f;
        }
        #pragma unroll
        for (int ni = 0; ni < 4; ++ni) {
            float sc = scn[ni];
            #pragma unroll
            for (int mi = 0; mi < 4; ++mi)
                #pragma unroll
                for (int j = 0; j < 4; ++j) {
                    float d2v = fmaf(-2.0f, acc[mi][ni][j], sr[mi * 4 + j] + sc);
                    float lo0 = fminf(c0s[ni], d2v), hi0 = fmaxf(c0s[ni], d2v);
                    c0s[ni] = lo0;
                    float lo1 = fminf(c1s[ni], hi0), hi1 = fmaxf(c1s[ni], hi0);
                    c1s[ni] = lo1;
                    c2s[ni] = fminf(c2s[ni], hi1);
                    cxs[ni] = fmaxf(cxs[ni], d2v);
                }
        }
        #pragma unroll
        for (int s = 16; s < 64; s <<= 1) {
            #pragma unroll
            for (int ni = 0; ni < 4; ++ni) {
                float b0 = __shfl_xor(c0s[ni], s);
                float b1 = __shfl_xor(c1s[ni], s);
                float b2 = __shfl_xor(c2s[ni], s);
                float bm = __shfl_xor(cxs[ni], s);
                float n0 = fminf(c0s[ni], b0);
                float n1 = fminf(fmaxf(c0s[ni], b0), fminf(c1s[ni], b1));
                float n2 = fminf(fminf(c2s[ni], b2),
                                 fminf(fmaxf(c0s[ni], b1), fmaxf(c1s[ni], b0)));
                c0s[ni] = n0; c1s[ni] = n1; c2s[ni] = n2; cxs[ni] = fmaxf(cxs[ni], bm);
            }
        }
        if (l < 16) {
            const int slot = 2 * I + wm;
            #pragma unroll
            for (int ni = 0; ni < 4; ++ni) {
                int colrow = c0 + wn * 64 + ni * 16 + l;
                part4[(size_t)slot * NROWS + colrow] =
                    make_float4(c0s[ni], c1s[ni], c2s[ni], cxs[ni]);
            }
        }
    }
}

// combine: fold all 64 slots per row (each slot written exactly once), then
// sqrt + prediction.
__global__ __launch_bounds__(256) void combine_kernel(const float4* __restrict__ part4,
                                                      float* __restrict__ out) {
    const int row = blockIdx.x * 256 + threadIdx.x;
    float m0 = 3.402823466e+38f, m1 = 3.402823466e+38f, m2 = 3.402823466e+38f;
    float mx = 0.0f;
    for (int s = 0; s < 64; ++s) {
        float4 t = part4[(size_t)s * NROWS + row];
        float n0 = fminf(m0, t.x);
        float n1 = fminf(fmaxf(m0, t.x), fminf(m1, t.y));
        float n2 = fminf(fminf(m2, t.z), fminf(fmaxf(m0, t.y), fmaxf(m1, t.x)));
        m0 = n0; m1 = n1; m2 = n2; mx = fmaxf(mx, t.w);
    }
    float d1 = sqrtf(fmaxf(m1, 0.0f) + 1e-12f);
    float d2 = sqrtf(fmaxf(m2, 0.0f) + 1e-12f);
    float dm = sqrtf(fmaxf(mx, 0.0f) + 1e-12f);
    out[row] = (d1 / d2 < 0.6f) ? 2.0f / (1.0f + expf(d1))
                                : 2.0f / (1.0f + 2.0f * expf(dm));
}

// ============================================================================
// Path B (fallback, fp32 VALU) if ws too small
// ============================================================================

__global__ __launch_bounds__(256) void sq_kernel(const float* __restrict__ x,
                                                 float* __restrict__ sq) {
    int wid = threadIdx.x >> 6;
    int lane = threadIdx.x & 63;
    int row = blockIdx.x * 4 + wid;
    const float* f = x + (size_t)row * CDIM;
    float4 v0 = *(const float4*)(f + lane * 8);
    float4 v1 = *(const float4*)(f + lane * 8 + 4);
    float s = v0.x*v0.x + v0.y*v0.y + v0.z*v0.z + v0.w*v0.w
            + v1.x*v1.x + v1.y*v1.y + v1.z*v1.z + v1.w*v1.w;
    #pragma unroll
    for (int o = 32; o > 0; o >>= 1) s += __shfl_xor(s, o);
    if (lane == 0) sq[row] = s;
}

__global__ __launch_bounds__(256, 2) void fcm_kernel(const float* __restrict__ x,
                                                     const float* __restrict__ sq,
                                                     float* __restrict__ out) {
    __shared__ __align__(16) float a_s[32][36];
    __shared__ __align__(16) float b_s[32][260];
    const int tid = threadIdx.x;
    const int ty = tid >> 6;
    const int tx = tid & 63;
    const int brow = blockIdx.x * 32;
    const int batch = brow >> 12;
    const int irow = brow & (NPTS - 1);
    const float* f = x + (size_t)batch * NPTS * CDIM;
    const float* sqb = sq + batch * NPTS;

    float srr[8];
    #pragma unroll
    for (int r = 0; r < 8; ++r) srr[r] = sqb[irow + ty * 8 + r];
    float m0[8], m1[8], m2[8], mx[8];
    #pragma unroll
    for (int r = 0; r < 8; ++r) {
        m0[r] = 3.402823466e+38f; m1[r] = 3.402823466e+38f;
        m2[r] = 3.402823466e+38f; mx[r] = 0.0f;
    }
    for (int ct = 0; ct < NPTS / 256; ++ct) {
        const int cbase = ct * 256;
        float acc[8][4];
        #pragma unroll
        for (int r = 0; r < 8; ++r)
            #pragma unroll
            for (int q = 0; q < 4; ++q) acc[r][q] = 0.0f;
        for (int kc = 0; kc < CDIM; kc += 32) {
            {
                int row = tid >> 3, l8 = tid & 7;
                float4 v = *(const float4*)(f + (size_t)(irow + row) * CDIM + kc + l8 * 4);
                a_s[l8 * 4 + 0][row] = v.x; a_s[l8 * 4 + 1][row] = v.y;
                a_s[l8 * 4 + 2][row] = v.z; a_s[l8 * 4 + 3][row] = v.w;
            }
            {
                int colb = tid >> 2, l4 = tid & 3;
                #pragma unroll
                for (int it = 0; it < 4; ++it) {
                    int col = colb + 64 * it;
                    const float* p = f + (size_t)(cbase + col) * CDIM + kc + l4 * 8;
                    float4 v0 = *(const float4*)p;
                    float4 v1 = *(const float4*)(p + 4);
                    b_s[l4 * 8 + 0][col] = v0.x; b_s[l4 * 8 + 1][col] = v0.y;
                    b_s[l4 * 8 + 2][col] = v0.z; b_s[l4 * 8 + 3][col] = v0.w;
                    b_s[l4 * 8 + 4][col] = v1.x; b_s[l4 * 8 + 5][col] = v1.y;
                    b_s[l4 * 8 + 6][col] = v1.z; b_s[l4 * 8 + 7][col] = v1.w;
                }
            }
            __syncthreads();
            #pragma unroll
            for (int k = 0; k < 32; ++k) {
                float a0[8], b0[4];
                *(float4*)&a0[0] = *(const float4*)&a_s[k][ty * 8];
                *(float4*)&a0[4] = *(const float4*)&a_s[k][ty * 8 + 4];
                *(float4*)&b0[0] = *(const float4*)&b_s[k][tx * 4];
                #pragma unroll
                for (int r = 0; r < 8; ++r)
                    #pragma unroll
                    for (int q = 0; q < 4; ++q)
                        acc[r][q] = fmaf(a0[r], b0[q], acc[r][q]);
            }
            __syncthreads();
        }
        #pragma unroll
        for (int q = 0; q < 4; ++q) {
            float sc = sqb[cbase + tx * 4 + q];
            #pragma unroll
            for (int r = 0; r < 8; ++r) {
                float d2v = fmaf(-2.0f, acc[r][q], srr[r] + sc);
                d2v = fmaxf(d2v, 0.0f);
                float d = sqrtf(d2v + 1e-12f);
                float lo = fminf(m0[r], d), hi = fmaxf(m0[r], d);
                m0[r] = lo;
                float lo1 = fminf(m1[r], hi), hi1 = fmaxf(m1[r], hi);
                m1[r] = lo1;
                m2[r] = fminf(m2[r], hi1);
                mx[r] = fmaxf(mx[r], d);
            }
        }
    }
    #pragma unroll
    for (int s = 1; s < 64; s <<= 1) {
        #pragma unroll
        for (int r = 0; r < 8; ++r) {
            float b0v = __shfl_xor(m0[r], s);
            float b1v = __shfl_xor(m1[r], s);
            float b2v = __shfl_xor(m2[r], s);
            float bmv = __shfl_xor(mx[r], s);
            float n0 = fminf(m0[r], b0v);
            float n1 = fminf(fmaxf(m0[r], b0v), fminf(m1[r], b1v));
            float n2 = fminf(fminf(m2[r], b2v),
                             fminf(fmaxf(m0[r], b1v), fmaxf(m1[r], b0v)));
            m0[r] = n0; m1[r] = n1; m2[r] = n2; mx[r] = fmaxf(mx[r], bmv);
        }
    }
    if (tx == 0) {
        #pragma unroll
        for (int r = 0; r < 8; ++r) {
            int grow = brow + ty * 8 + r;
            float d1 = m1[r], d2nd = m2[r], dmaxv = mx[r];
            float pred = (d1 / d2nd < 0.6f) ? 2.0f / (1.0f + expf(d1))
                                            : 2.0f / (1.0f + 2.0f * expf(dmaxv));
            out[grow] = pred;
        }
    }
}

extern "C" void kernel_launch(void* const* d_in, const int* in_sizes, int n_in,
                              void* d_out, int out_size, void* d_ws, size_t ws_size,
                              hipStream_t stream) {
    const float* x = (const float*)d_in[0];
    float* out = (float*)d_out;

    const size_t plane = (size_t)NROWS * CDIM * sizeof(half_t);      // 16 MB
    const size_t partb = (size_t)64 * NROWS * sizeof(float4);        // 16 MB
    const size_t need = plane + NROWS * sizeof(float) + partb;

    if (ws_size >= need) {
        half_t* hi = (half_t*)d_ws;
        float* sq = (float*)((char*)d_ws + plane);
        float4* part4 = (float4*)((char*)d_ws + plane + NROWS * sizeof(float));
        prep_kernel<<<dim3(NROWS / 4), dim3(256), 0, stream>>>(x, hi, sq);
        fcm_sym<<<dim3(4 * NTILES), dim3(256), 0, stream>>>(hi, sq, part4);
        combine_kernel<<<dim3(NROWS / 256), dim3(256), 0, stream>>>(part4, out);
    } else {
        float* sqw = (float*)d_ws;
        sq_kernel<<<dim3(4096), dim3(256), 0, stream>>>(x, sqw);
        fcm_kernel<<<dim3(512), dim3(256), 0, stream>>>(x, sqw, out);
    }
}